// Round 4
// baseline (137.261 us; speedup 1.0000x reference)
//
#include <hip/hip_runtime.h>

#define IN_N   4096
#define OW     4084          // (4096 + 2*1 - 15) + 1
#define KS     15
#define TILE   64            // 64x64 output tile (4 waves x 16 rows)
#define XROWS  78            // TILE + KS - 1
#define XS     88            // LDS row stride (halfwords)
#define NBXT   64            // total x tiles
#define NBY    64            // total y tiles
#define TPB    4             // tiles per block (along x)

typedef __attribute__((ext_vector_type(8))) short v8s;   // 8 x bf16 frag
typedef __attribute__((ext_vector_type(4))) float v4f;   // C/D frag

__device__ __forceinline__ unsigned short f2bf(float f) {
    union { float f; unsigned u; } c; c.f = f;
    unsigned r = c.u + 0x7fff + ((c.u >> 16) & 1);   // RTNE (inputs finite)
    return (unsigned short)(r >> 16);
}
__device__ __forceinline__ unsigned pack2(float a, float b) {
    return (unsigned)f2bf(a) | ((unsigned)f2bf(b) << 16);
}

// ---- pre-kernel: build the 15 banded-B MFMA fragments once into d_ws ----
// B_ky[k][n] = w[ky, k-n] if 0 <= k-n < 15 else 0
// lane e holds B[k = (e>>4)*8 + j][n = e&15], j = 0..7
__global__ void build_B(const float* __restrict__ w, unsigned short* __restrict__ Bg) {
    int ky = blockIdx.x, e = threadIdx.x;
    int n = e & 15, quad = e >> 4;
    unsigned short vals[8];
    #pragma unroll
    for (int j = 0; j < 8; ++j) {
        int d = quad * 8 + j - n;
        vals[j] = (d >= 0 && d < KS) ? f2bf(w[ky * KS + d]) : (unsigned short)0;
    }
    *(v8s*)(&Bg[(ky * 64 + e) * 8]) = *(const v8s*)vals;
}

__global__ __launch_bounds__(256, 4) void conv2d_mfma3(
    const float* __restrict__ x, const unsigned short* __restrict__ Bg,
    const float* __restrict__ bias, float* __restrict__ out)
{
    __shared__ unsigned short buf[2][XROWS * XS] __attribute__((aligned(16)));

    const int tid = threadIdx.x;
    const int gbx = blockIdx.x, by = blockIdx.y;
    const int Y0  = by * TILE;
    const int bx0 = gbx * TPB;

    // staging geometry: 240 threads, thread = (col-pair tx, row ty), 13 row-passes
    const int tx = tid % 40;
    const int ty = tid / 40;
    const bool act = (ty < 6);

    const int lane = tid & 63, wv = tid >> 6;
    const int m = lane & 15, quad = lane >> 4;
    const v8s* Bgv = (const v8s*)Bg;
    const float bv = bias[0];

    float pf0[13], pf1[13];   // prefetch registers for next tile

    auto load_tile = [&](int bx) {
        if (!act) return;
        const int X0 = bx * TILE;
        const bool fast = (bx > 0) & (bx < NBXT - 1) & (by > 0) & (by < NBY - 1);
        if (fast) {
            const float* xr = x + (size_t)(Y0 - 1 + ty) * IN_N + (X0 - 1 + 2 * tx);
            #pragma unroll
            for (int i = 0; i < 13; ++i) {
                pf0[i] = xr[0]; pf1[i] = xr[1];
                xr += 6 * (size_t)IN_N;
            }
        } else {
            const int gc0 = X0 - 1 + 2 * tx;
            #pragma unroll
            for (int i = 0; i < 13; ++i) {
                int gr = Y0 - 1 + ty + 6 * i;
                float f0 = 0.0f, f1 = 0.0f;
                if ((unsigned)gr < (unsigned)IN_N) {
                    const float* xr = x + (size_t)gr * IN_N;
                    if ((unsigned)gc0       < (unsigned)IN_N) f0 = xr[gc0];
                    if ((unsigned)(gc0 + 1) < (unsigned)IN_N) f1 = xr[gc0 + 1];
                }
                pf0[i] = f0; pf1[i] = f1;
            }
        }
    };

    auto store_tile = [&](unsigned short* b) {
        if (!act) return;
        unsigned* dst = (unsigned*)&b[ty * XS + 2 * tx];   // XS even -> 4B aligned
        #pragma unroll
        for (int i = 0; i < 13; ++i) {
            *dst = pack2(pf0[i], pf1[i]);
            dst += 3 * XS;                                 // 6 rows = 3*XS dwords
        }
    };

    // prologue: stage tile 0
    load_tile(bx0);
    store_tile(buf[0]);
    __syncthreads();

    #pragma unroll
    for (int j = 0; j < TPB; ++j) {
        const int bx = bx0 + j;
        const int X0 = bx * TILE;

        // issue next tile's global loads NOW; vmcnt wait lands after compute
        if (j < TPB - 1) load_tile(bx + 1);

        // ---- compute tile j from buf[j&1] ----
        v4f acc[4];
        #pragma unroll
        for (int t = 0; t < 4; ++t) acc[t] = (v4f){0.f, 0.f, 0.f, 0.f};

        const unsigned short* arow = &buf[j & 1][(wv * 16 + m) * XS + quad * 8];
        v8s bcur = Bgv[lane];
        #pragma unroll
        for (int ky = 0; ky < KS; ++ky) {
            v8s bnext = (ky < KS - 1) ? Bgv[(ky + 1) * 64 + lane] : bcur;
            v8s a0 = *(const v8s*)(arow + 0);
            v8s a1 = *(const v8s*)(arow + 16);
            v8s a2 = *(const v8s*)(arow + 32);
            v8s a3 = *(const v8s*)(arow + 48);
            acc[0] = __builtin_amdgcn_mfma_f32_16x16x32_bf16(a0, bcur, acc[0], 0, 0, 0);
            acc[1] = __builtin_amdgcn_mfma_f32_16x16x32_bf16(a1, bcur, acc[1], 0, 0, 0);
            acc[2] = __builtin_amdgcn_mfma_f32_16x16x32_bf16(a2, bcur, acc[2], 0, 0, 0);
            acc[3] = __builtin_amdgcn_mfma_f32_16x16x32_bf16(a3, bcur, acc[3], 0, 0, 0);
            arow += XS;
            bcur = bnext;
        }

        // ---- epilogue: D row = quad*4 + r, col = m + t*16 ----
        const int orow0 = Y0 + wv * 16 + quad * 4;
        const int ocol0 = X0 + m;
        if ((bx < NBXT - 1) & (by < NBY - 1)) {
            float* o0 = &out[(size_t)orow0 * OW + ocol0];
            #pragma unroll
            for (int t = 0; t < 4; ++t)
                #pragma unroll
                for (int r = 0; r < 4; ++r)
                    o0[(size_t)r * OW + t * 16] = acc[t][r] + bv;
        } else {
            #pragma unroll
            for (int t = 0; t < 4; ++t) {
                int oc = ocol0 + t * 16;
                if (oc < OW) {
                    #pragma unroll
                    for (int r = 0; r < 4; ++r) {
                        int orow = orow0 + r;
                        if (orow < OW)
                            out[(size_t)orow * OW + oc] = acc[t][r] + bv;
                    }
                }
            }
        }

        // ---- convert + write next tile into the other buffer ----
        if (j < TPB - 1) {
            store_tile(&buf[(j + 1) & 1][0]);
            __syncthreads();
        }
    }
}

extern "C" void kernel_launch(void* const* d_in, const int* in_sizes, int n_in,
                              void* d_out, int out_size, void* d_ws, size_t ws_size,
                              hipStream_t stream) {
    const float* x    = (const float*)d_in[0];
    const float* w    = (const float*)d_in[1];
    const float* bias = (const float*)d_in[2];
    float* out        = (float*)d_out;
    unsigned short* Bg = (unsigned short*)d_ws;     // 15 KiB scratch

    build_B<<<dim3(KS), dim3(64), 0, stream>>>(w, Bg);
    dim3 grid(NBXT / TPB, NBY);                     // 16 x 64 = 1024 blocks
    conv2d_mfma3<<<grid, dim3(256), 0, stream>>>(x, Bg, bias, out);
}